// Round 1
// baseline (918.235 us; speedup 1.0000x reference)
//
#include <hip/hip_runtime.h>
#include <hip/hip_bf16.h>

#define NB 16
#define DDIM 768
#define HH 28
#define WWID 28
#define NP 784
#define NTOT 12544
#define MTOT 16384
#define NCAND 8
#define TOTCAND 128
#define OUTHW 224

typedef __attribute__((ext_vector_type(8))) short bf16x8;
typedef __attribute__((ext_vector_type(4))) float f32x4;

__device__ inline unsigned long long packmin(float v, int idx) {
  unsigned u = __float_as_uint(v);
  u = (u & 0x80000000u) ? ~u : (u | 0x80000000u);
  return ((unsigned long long)u << 32) | (unsigned)idx;
}
__device__ inline float unpackval(unsigned long long p) {
  unsigned hi = (unsigned)(p >> 32);
  return (hi & 0x80000000u) ? __uint_as_float(hi ^ 0x80000000u) : __uint_as_float(~hi);
}

__device__ inline void gload16(const void* g, void* l) {
  __builtin_amdgcn_global_load_lds((const __attribute__((address_space(1))) unsigned int*)g,
                                   (__attribute__((address_space(3))) unsigned int*)l, 16, 0, 0);
}

// ---------------- init ----------------
__global__ void k_init(unsigned long long* rowmin, float* a2) {
  int i = blockIdx.x * 256 + threadIdx.x;
  if (i < NTOT) { rowmin[i] = ~0ull; a2[i] = 0.f; }
}

// ---------- avgpool3x3 + transpose to [N,D] + bf16 + a2 partials ----------
__global__ void k_prep_emb(const float* __restrict__ feat, float* __restrict__ emb,
                           __hip_bfloat16* __restrict__ embh, float* __restrict__ a2) {
  const int dt = blockIdx.x;   // 12
  const int ht = blockIdx.y;   // 7
  const int b  = blockIdx.z;   // 16
  const int d0 = dt * 64;
  const int h0 = ht * 4;
  const int n0 = b * NP + ht * 112;
  __shared__ float halo[64][169];  // 6 rows x 28 (+1 pad)
  __shared__ float a2s[112];
  const int t = threadIdx.x;
  for (int i = t; i < 112; i += 256) a2s[i] = 0.f;
  for (int idx = t; idx < 64 * 168; idx += 256) {
    int dd = idx / 168, p = idx % 168;
    int rr = p / 28, w = p % 28;
    int h = h0 - 1 + rr;
    float v = 0.f;
    if (h >= 0 && h < HH)
      v = feat[(((size_t)b * DDIM + d0 + dd) * HH + h) * WWID + w];
    halo[dd][p] = v;
  }
  __syncthreads();
  for (int idx = t; idx < 112 * 64; idx += 256) {
    int nn = idx >> 6, dd = idx & 63;
    int hl = nn / 28, w = nn % 28;
    float s = 0.f;
#pragma unroll
    for (int dr = 0; dr < 3; ++dr) {
      const float* row = &halo[dd][(hl + dr) * 28];
      float c = row[w];
      if (w > 0) c += row[w - 1];
      if (w < 27) c += row[w + 1];
      s += c;
    }
    float v = s * (1.f / 9.f);
    size_t o = (size_t)(n0 + nn) * DDIM + d0 + dd;
    emb[o] = v;
    embh[o] = __float2bfloat16(v);
    atomicAdd(&a2s[nn], v * v);
  }
  __syncthreads();
  for (int i = t; i < 112; i += 256) atomicAdd(&a2[n0 + i], a2s[i]);
}

// ---------- memory bank: bf16 + norms ----------
__global__ void k_prep_mb(const float* __restrict__ mb, __hip_bfloat16* __restrict__ mbh,
                          float* __restrict__ b2) {
  int m = blockIdx.x, t = threadIdx.x;
  const float* r = mb + (size_t)m * DDIM;
  float s = 0.f;
#pragma unroll
  for (int j = 0; j < 3; ++j) {
    float v = r[t + j * 256];
    s += v * v;
    mbh[(size_t)m * DDIM + t + j * 256] = __float2bfloat16(v);
  }
  for (int o = 32; o; o >>= 1) s += __shfl_down(s, o);
  __shared__ float ws4[4];
  if ((t & 63) == 0) ws4[t >> 6] = s;
  __syncthreads();
  if (t == 0) b2[m] = ws4[0] + ws4[1] + ws4[2] + ws4[3];
}

// ---------- main bf16 MFMA GEMM, fused min/argmin (MODE 0) or store (MODE 1) ----------
template <int MODE>
__global__ __launch_bounds__(256) void k_gemm(const __hip_bfloat16* __restrict__ A,
                                              const __hip_bfloat16* __restrict__ Bm,
                                              const float* __restrict__ b2,
                                              unsigned long long* rowmin, float* dC) {
  __shared__ short As[128 * 32];
  __shared__ short Bs[128 * 32];
  __shared__ unsigned long long rmin[128][2];
  const int t = threadIdx.x;
  const int m0 = blockIdx.x * 128;
  const int n0 = blockIdx.y * 128;
  const int w = t >> 6, l = t & 63;
  const int wr = w >> 1, wc = w & 1;
  const int lc = l & 15, lg = l >> 4;
  f32x4 acc[4][4] = {};
  for (int kt = 0; kt < 24; ++kt) {
    const int k0 = kt * 32;
    __syncthreads();
#pragma unroll
    for (int j = 0; j < 2; ++j) {
      int flat = t + j * 256;
      int row = flat >> 2, kc = flat & 3;
      gload16(A + (size_t)(n0 + row) * DDIM + k0 + kc * 8, (char*)As + flat * 16);
      gload16(Bm + (size_t)(m0 + row) * DDIM + k0 + kc * 8, (char*)Bs + flat * 16);
    }
    __syncthreads();
    bf16x8 av[4], bv[4];
#pragma unroll
    for (int i = 0; i < 4; ++i) {
      av[i] = *(const bf16x8*)(As + (wr * 64 + i * 16 + lc) * 32 + lg * 8);
      bv[i] = *(const bf16x8*)(Bs + (wc * 64 + i * 16 + lc) * 32 + lg * 8);
    }
#pragma unroll
    for (int i = 0; i < 4; ++i)
#pragma unroll
      for (int j = 0; j < 4; ++j)
        acc[i][j] = __builtin_amdgcn_mfma_f32_16x16x32_bf16(av[i], bv[j], acc[i][j], 0, 0, 0);
  }
  __syncthreads();
  float b2v[4];
#pragma unroll
  for (int j = 0; j < 4; ++j) b2v[j] = b2[m0 + wc * 64 + j * 16 + lc];
  if constexpr (MODE == 0) {
#pragma unroll
    for (int i = 0; i < 4; ++i)
#pragma unroll
      for (int r = 0; r < 4; ++r) {
        unsigned long long best = ~0ull;
#pragma unroll
        for (int j = 0; j < 4; ++j) {
          int col = m0 + wc * 64 + j * 16 + lc;
          float v = b2v[j] - 2.f * acc[i][j][r];
          unsigned long long p = packmin(v, col);
          best = best < p ? best : p;
        }
        for (int o = 1; o < 16; o <<= 1) {
          unsigned long long o2 = (unsigned long long)__shfl_xor((long long)best, o);
          best = best < o2 ? best : o2;
        }
        if (lc == 0) rmin[wr * 64 + i * 16 + lg * 4 + r][wc] = best;
      }
    __syncthreads();
    if (t < 128) {
      unsigned long long v = rmin[t][0] < rmin[t][1] ? rmin[t][0] : rmin[t][1];
      atomicMin(&rowmin[n0 + t], v);
    }
  } else {
#pragma unroll
    for (int i = 0; i < 4; ++i)
#pragma unroll
      for (int r = 0; r < 4; ++r) {
        int crow = wr * 64 + i * 16 + lg * 4 + r;
#pragma unroll
        for (int j = 0; j < 4; ++j) {
          int col = m0 + wc * 64 + j * 16 + lc;
          dC[(size_t)crow * MTOT + col] = b2v[j] - 2.f * acc[i][j][r];
        }
      }
  }
}

// ---------- patch scores + locations ----------
__global__ void k_scores(const unsigned long long* __restrict__ rowmin,
                         const float* __restrict__ a2, float* __restrict__ ps,
                         int* __restrict__ pl) {
  int n = blockIdx.x * 256 + threadIdx.x;
  if (n >= NTOT) return;
  unsigned long long v = rowmin[n];
  float d2 = a2[n] + unpackval(v);
  ps[n] = sqrtf(fmaxf(d2, 0.f));
  pl[n] = (int)(v & 0xffffffffu);
}

// ---------- top-8 candidate patches per batch ----------
__global__ void k_topc(const float* __restrict__ ps, int* __restrict__ cand_n) {
  int b = blockIdx.x, t = threadIdx.x;
  __shared__ float sv[NP];
  __shared__ float rv[256];
  __shared__ int ri[256];
  for (int i = t; i < NP; i += 256) sv[i] = ps[b * NP + i];
  __syncthreads();
  for (int c = 0; c < NCAND; ++c) {
    float bvv = -1e30f; int bi = 0;
    for (int i = t; i < NP; i += 256)
      if (sv[i] > bvv) { bvv = sv[i]; bi = i; }
    rv[t] = bvv; ri[t] = bi;
    __syncthreads();
    for (int s = 128; s; s >>= 1) {
      if (t < s) {
        if (rv[t + s] > rv[t] || (rv[t + s] == rv[t] && ri[t + s] < ri[t])) {
          rv[t] = rv[t + s]; ri[t] = ri[t + s];
        }
      }
      __syncthreads();
    }
    if (t == 0) { cand_n[b * NCAND + c] = b * NP + ri[0]; sv[ri[0]] = -2e30f; }
    __syncthreads();
  }
}

// ---------- gather candidate bf16 rows ----------
__global__ void k_gather(const int* __restrict__ cand_n, const __hip_bfloat16* __restrict__ embh,
                         __hip_bfloat16* __restrict__ ac) {
  int c = blockIdx.x, t = threadIdx.x;
  int n = cand_n[c];
  for (int j = t; j < DDIM; j += 256) ac[(size_t)c * DDIM + j] = embh[(size_t)n * DDIM + j];
}

// ---------- exact refinement of candidate rows ----------
__global__ void k_refine(const float* __restrict__ dcand, const int* __restrict__ cand_n,
                         const float* __restrict__ emb, const float* __restrict__ mbf,
                         const float* __restrict__ a2, const float* __restrict__ b2,
                         float* __restrict__ cscore, int* __restrict__ cloc) {
  int c = blockIdx.x, t = threadIdx.x;
  int n = cand_n[c];
  const float* row = dcand + (size_t)c * MTOT;
  float mn = 1e30f;
  for (int m = t; m < MTOT; m += 256) mn = fminf(mn, row[m]);
  __shared__ float red[256];
  red[t] = mn; __syncthreads();
  for (int s = 128; s; s >>= 1) { if (t < s) red[t] = fminf(red[t], red[t + s]); __syncthreads(); }
  float gmin = red[0];
  __shared__ int list[64];
  __shared__ int cnt;
  if (t == 0) cnt = 0;
  __syncthreads();
  for (int m = t; m < MTOT; m += 256) {
    if (row[m] <= gmin + 8.0f) {
      int p = atomicAdd(&cnt, 1);
      if (p < 64) list[p] = m;
    }
  }
  __syncthreads();
  int L = cnt < 64 ? cnt : 64;
  __shared__ float er[DDIM];
  for (int j = t; j < DDIM; j += 256) er[j] = emb[(size_t)n * DDIM + j];
  __syncthreads();
  int wv = t >> 6, ln = t & 63;
  unsigned long long best = ~0ull;
  for (int li = wv; li < L; li += 4) {
    int m = list[li];
    const float* mr = mbf + (size_t)m * DDIM;
    float s = 0.f;
    for (int j = ln; j < DDIM; j += 64) s += er[j] * mr[j];
    for (int o = 32; o; o >>= 1) s += __shfl_down(s, o);
    if (ln == 0) {
      float d2 = a2[n] + b2[m] - 2.f * s;
      unsigned long long p = packmin(d2, m);
      best = best < p ? best : p;
    }
  }
  __shared__ unsigned long long bw[4];
  if (ln == 0) bw[wv] = best;
  __syncthreads();
  if (t == 0) {
    unsigned long long bb = bw[0];
    for (int i = 1; i < 4; ++i) bb = bb < bw[i] ? bb : bw[i];
    float d2 = unpackval(bb);
    cscore[c] = sqrtf(fmaxf(d2, 0.f));
    cloc[c] = (int)(bb & 0xffffffffu);
  }
}

// ---------- pick per-batch winner ----------
__global__ void k_winner(const int* __restrict__ cand_n, const float* __restrict__ cscore,
                         const int* __restrict__ cloc, float* __restrict__ wscore,
                         int* __restrict__ wloc, int* __restrict__ wn) {
  int b = threadIdx.x;
  if (b < NB) {
    float bs = -1e30f; int bc = 0;
    for (int c = 0; c < NCAND; ++c) {
      float s = cscore[b * NCAND + c];
      if (s > bs) { bs = s; bc = c; }
    }
    wscore[b] = bs;
    wloc[b] = cloc[b * NCAND + bc];
    wn[b] = cand_n[b * NCAND + bc];
  }
}

// ---------- distances nn_sample -> all memory bank rows (d2, no sqrt) ----------
__global__ void k_d2nn(const float* __restrict__ mbf, const int* __restrict__ wloc,
                       const float* __restrict__ b2, float* __restrict__ d2nn) {
  __shared__ float nnr[16][64];
  __shared__ float mbr[16][65];
  __shared__ int wl[16];
  int t = threadIdx.x;
  int m0 = blockIdx.x * 16;
  if (t < 16) wl[t] = wloc[t];
  __syncthreads();
  int b = t >> 4, mi = t & 15;
  float acc = 0.f;
  for (int k0 = 0; k0 < DDIM; k0 += 64) {
    __syncthreads();
    for (int i = t; i < 1024; i += 256) {
      int r = i >> 6, kk = i & 63;
      nnr[r][kk] = mbf[(size_t)wl[r] * DDIM + k0 + kk];
      mbr[r][kk] = mbf[(size_t)(m0 + r) * DDIM + k0 + kk];
    }
    __syncthreads();
#pragma unroll 16
    for (int kk = 0; kk < 64; ++kk) acc += nnr[b][kk] * mbr[mi][kk];
  }
  int m = m0 + mi;
  d2nn[b * MTOT + m] = b2[wl[b]] + b2[m] - 2.f * acc;
}

// ---------- top-9 nearest of nn_sample ----------
__global__ void k_top9(const float* __restrict__ d2nn, int* __restrict__ supidx) {
  int b = blockIdx.x, t = threadIdx.x;
  const float* row = d2nn + (size_t)b * MTOT;
  __shared__ unsigned long long red[256];
  __shared__ int chosen[9];
  for (int k = 0; k < 9; ++k) {
    unsigned long long best = ~0ull;
    for (int m = t; m < MTOT; m += 256) {
      bool skip = false;
      for (int j = 0; j < k; ++j)
        if (chosen[j] == m) skip = true;
      if (!skip) {
        unsigned long long p = packmin(row[m], m);
        best = best < p ? best : p;
      }
    }
    red[t] = best; __syncthreads();
    for (int s = 128; s; s >>= 1) {
      if (t < s) red[t] = red[t] < red[t + s] ? red[t] : red[t + s];
      __syncthreads();
    }
    if (t == 0) { chosen[k] = (int)(red[0] & 0xffffffffu); supidx[b * 9 + k] = chosen[k]; }
    __syncthreads();
  }
}

// ---------- anomaly score ----------
__global__ void k_anom(const float* __restrict__ emb, const float* __restrict__ mbf,
                       const int* __restrict__ wn, const int* __restrict__ supidx,
                       const float* __restrict__ wscore, float* __restrict__ out_anom) {
  int b = blockIdx.x, t = threadIdx.x;
  __shared__ float er[DDIM];
  __shared__ float dist[9];
  __shared__ float red[256];
  int n = wn[b];
  for (int j = t; j < DDIM; j += 256) er[j] = emb[(size_t)n * DDIM + j];
  __syncthreads();
  for (int k = 0; k < 9; ++k) {
    int m = supidx[b * 9 + k];
    const float* mr = mbf + (size_t)m * DDIM;
    float s = 0.f;
    for (int j = t; j < DDIM; j += 256) { float d = er[j] - mr[j]; s += d * d; }
    red[t] = s; __syncthreads();
    for (int st = 128; st; st >>= 1) { if (t < st) red[t] += red[t + st]; __syncthreads(); }
    if (t == 0) dist[k] = sqrtf(fmaxf(red[0], 0.f));
    __syncthreads();
  }
  if (t == 0) {
    float mx = dist[0];
    for (int k = 1; k < 9; ++k) mx = fmaxf(mx, dist[k]);
    float sum = 0.f;
    for (int k = 0; k < 9; ++k) sum += expf(dist[k] - mx);
    float w = 1.f - expf(dist[0] - mx) / sum;
    out_anom[b] = w * wscore[b];
  }
}

// ---------- bilinear 28->224 (half-pixel, clamp == jax renormalized) ----------
__global__ void k_bilinear(const float* __restrict__ ps, float* __restrict__ amap) {
  int idx = blockIdx.x * 256 + threadIdx.x;
  if (idx >= NB * OUTHW * OUTHW) return;
  int x = idx % OUTHW, y = (idx / OUTHW) % OUTHW, b = idx / (OUTHW * OUTHW);
  float sy = (y + 0.5f) * 0.125f - 0.5f;
  float sx = (x + 0.5f) * 0.125f - 0.5f;
  int iy = (int)floorf(sy), ix = (int)floorf(sx);
  float fy = sy - iy, fx = sx - ix;
  int y0 = min(27, max(0, iy)), y1 = min(27, max(0, iy + 1));
  int x0 = min(27, max(0, ix)), x1 = min(27, max(0, ix + 1));
  const float* p = ps + b * NP;
  float v = (1.f - fy) * ((1.f - fx) * p[y0 * 28 + x0] + fx * p[y0 * 28 + x1]) +
            fy * ((1.f - fx) * p[y1 * 28 + x0] + fx * p[y1 * 28 + x1]);
  amap[idx] = v;
}

__device__ inline void gauss_coefs(float* g, int t) {
  if (t == 0) {
    float tmp[33]; float s = 0.f;
    for (int j = 0; j < 33; ++j) { float c = (float)(j - 16); tmp[j] = expf(-(c * c) / 32.f); s += tmp[j]; }
    for (int j = 0; j < 33; ++j) g[j] = tmp[j] / s;
  }
}

__global__ void k_blur_h(const float* __restrict__ in, float* __restrict__ out) {
  int by = blockIdx.x;  // b*224 + y
  int t = threadIdx.x;
  __shared__ float g[33];
  __shared__ float rowbuf[OUTHW];
  gauss_coefs(g, t);
  for (int i = t; i < OUTHW; i += 256) rowbuf[i] = in[(size_t)by * OUTHW + i];
  __syncthreads();
  if (t < OUTHW) {
    float s = 0.f;
#pragma unroll
    for (int j = -16; j <= 16; ++j) {
      int x = t + j;
      x = x < 0 ? -x : (x > 223 ? 446 - x : x);
      s += g[j + 16] * rowbuf[x];
    }
    out[(size_t)by * OUTHW + t] = s;
  }
}

__global__ void k_blur_v(const float* __restrict__ in, float* __restrict__ out) {
  int xt = blockIdx.x, b = blockIdx.y, t = threadIdx.x;
  __shared__ float g[33];
  __shared__ float strip[OUTHW][32];
  gauss_coefs(g, t);
  int x0 = xt * 32;
  for (int i = t; i < OUTHW * 32; i += 256) {
    int y = i >> 5, xx = i & 31;
    strip[y][xx] = in[((size_t)b * OUTHW + y) * OUTHW + x0 + xx];
  }
  __syncthreads();
  for (int i = t; i < OUTHW * 32; i += 256) {
    int y = i >> 5, xx = i & 31;
    float s = 0.f;
#pragma unroll
    for (int j = -16; j <= 16; ++j) {
      int yy = y + j;
      yy = yy < 0 ? -yy : (yy > 223 ? 446 - yy : yy);
      s += g[j + 16] * strip[yy][xx];
    }
    out[((size_t)b * OUTHW + y) * OUTHW + x0 + xx] = s;
  }
}

extern "C" void kernel_launch(void* const* d_in, const int* in_sizes, int n_in,
                              void* d_out, int out_size, void* d_ws, size_t ws_size,
                              hipStream_t stream) {
  const float* feat = (const float*)d_in[0];
  const float* mbf = (const float*)d_in[1];
  float* out = (float*)d_out;

  char* ws = (char*)d_ws;
  size_t off = 0;
  auto alloc = [&](size_t bytes) {
    void* p = ws + off;
    off = (off + bytes + 255) & ~(size_t)255;
    return p;
  };
  float* emb = (float*)alloc((size_t)NTOT * DDIM * 4);
  __hip_bfloat16* embh = (__hip_bfloat16*)alloc((size_t)NTOT * DDIM * 2);
  __hip_bfloat16* mbh = (__hip_bfloat16*)alloc((size_t)MTOT * DDIM * 2);
  float* a2 = (float*)alloc(NTOT * 4);
  float* b2 = (float*)alloc(MTOT * 4);
  unsigned long long* rowmin = (unsigned long long*)alloc(NTOT * 8);
  float* pscore = (float*)alloc(NTOT * 4);
  int* ploc = (int*)alloc(NTOT * 4);
  __hip_bfloat16* acand = (__hip_bfloat16*)alloc((size_t)TOTCAND * DDIM * 2);
  float* dcand = (float*)alloc((size_t)TOTCAND * MTOT * 4);
  int* cand_n = (int*)alloc(TOTCAND * 4);
  float* cscore = (float*)alloc(TOTCAND * 4);
  int* cloc = (int*)alloc(TOTCAND * 4);
  float* wscore = (float*)alloc(NB * 4);
  int* wloc = (int*)alloc(NB * 4);
  int* wn = (int*)alloc(NB * 4);
  int* supidx = (int*)alloc(NB * 9 * 4);
  float* d2nn = (float*)alloc((size_t)NB * MTOT * 4);
  float* amap_pre = (float*)alloc((size_t)NB * OUTHW * OUTHW * 4);
  float* amap_tmp = (float*)alloc((size_t)NB * OUTHW * OUTHW * 4);

  k_init<<<49, 256, 0, stream>>>(rowmin, a2);
  k_prep_emb<<<dim3(12, 7, 16), 256, 0, stream>>>(feat, emb, embh, a2);
  k_prep_mb<<<MTOT, 256, 0, stream>>>(mbf, mbh, b2);
  k_gemm<0><<<dim3(128, 98), 256, 0, stream>>>(embh, mbh, b2, rowmin, nullptr);
  k_scores<<<49, 256, 0, stream>>>(rowmin, a2, pscore, ploc);
  k_topc<<<NB, 256, 0, stream>>>(pscore, cand_n);
  k_gather<<<TOTCAND, 256, 0, stream>>>(cand_n, embh, acand);
  k_gemm<1><<<dim3(128, 1), 256, 0, stream>>>(acand, mbh, b2, nullptr, dcand);
  k_refine<<<TOTCAND, 256, 0, stream>>>(dcand, cand_n, emb, mbf, a2, b2, cscore, cloc);
  k_winner<<<1, 256, 0, stream>>>(cand_n, cscore, cloc, wscore, wloc, wn);
  k_d2nn<<<MTOT / 16, 256, 0, stream>>>(mbf, wloc, b2, d2nn);
  k_top9<<<NB, 256, 0, stream>>>(d2nn, supidx);
  k_anom<<<NB, 256, 0, stream>>>(emb, mbf, wn, supidx, wscore, out + NB * OUTHW * OUTHW);
  k_bilinear<<<(NB * OUTHW * OUTHW + 255) / 256, 256, 0, stream>>>(pscore, amap_pre);
  k_blur_h<<<NB * OUTHW, 256, 0, stream>>>(amap_pre, amap_tmp);
  k_blur_v<<<dim3(7, NB), 256, 0, stream>>>(amap_tmp, out);
}

// Round 2
// 905.213 us; speedup vs baseline: 1.0144x; 1.0144x over previous
//
#include <hip/hip_runtime.h>
#include <hip/hip_bf16.h>

#define NB 16
#define DDIM 768
#define HH 28
#define WWID 28
#define NP 784
#define NTOT 12544
#define MTOT 16384
#define NCAND 8
#define TOTCAND 128
#define OUTHW 224
#define NKT 24  // 768 / 32

typedef __attribute__((ext_vector_type(8))) short bf16x8;
typedef __attribute__((ext_vector_type(4))) float f32x4;
typedef unsigned long long u64;

__device__ inline u64 packmin(float v, int idx) {
  unsigned u = __float_as_uint(v);
  u = (u & 0x80000000u) ? ~u : (u | 0x80000000u);
  return ((u64)u << 32) | (unsigned)idx;
}
__device__ inline float unpackval(u64 p) {
  unsigned hi = (unsigned)(p >> 32);
  return (hi & 0x80000000u) ? __uint_as_float(hi ^ 0x80000000u) : __uint_as_float(~hi);
}

__device__ inline void gload16(const void* g, void* l) {
  __builtin_amdgcn_global_load_lds((const __attribute__((address_space(1))) unsigned int*)g,
                                   (__attribute__((address_space(3))) unsigned int*)l, 16, 0, 0);
}

// ---------------- init ----------------
__global__ void k_init(u64* rowmin, float* a2) {
  int i = blockIdx.x * 256 + threadIdx.x;
  if (i < NTOT) { rowmin[i] = ~0ull; a2[i] = 0.f; }
}

// ---------- avgpool3x3 + transpose to [N,D] + bf16 + a2 partials ----------
__global__ void k_prep_emb(const float* __restrict__ feat, float* __restrict__ emb,
                           __hip_bfloat16* __restrict__ embh, float* __restrict__ a2) {
  const int dt = blockIdx.x;   // 12
  const int ht = blockIdx.y;   // 7
  const int b  = blockIdx.z;   // 16
  const int d0 = dt * 64;
  const int h0 = ht * 4;
  const int n0 = b * NP + ht * 112;
  __shared__ float halo[64][169];  // 6 rows x 28 (+1 pad)
  __shared__ float a2s[112];
  const int t = threadIdx.x;
  for (int i = t; i < 112; i += 256) a2s[i] = 0.f;
  for (int idx = t; idx < 64 * 168; idx += 256) {
    int dd = idx / 168, p = idx % 168;
    int rr = p / 28, w = p % 28;
    int h = h0 - 1 + rr;
    float v = 0.f;
    if (h >= 0 && h < HH)
      v = feat[(((size_t)b * DDIM + d0 + dd) * HH + h) * WWID + w];
    halo[dd][p] = v;
  }
  __syncthreads();
  for (int idx = t; idx < 112 * 64; idx += 256) {
    int nn = idx >> 6, dd = idx & 63;
    int hl = nn / 28, w = nn % 28;
    float s = 0.f;
#pragma unroll
    for (int dr = 0; dr < 3; ++dr) {
      const float* row = &halo[dd][(hl + dr) * 28];
      float c = row[w];
      if (w > 0) c += row[w - 1];
      if (w < 27) c += row[w + 1];
      s += c;
    }
    float v = s * (1.f / 9.f);
    size_t o = (size_t)(n0 + nn) * DDIM + d0 + dd;
    emb[o] = v;
    embh[o] = __float2bfloat16(v);
    // nn is wave-uniform (dd == lane): shuffle-reduce, single writer (no atomic serialization)
    float vv = v * v;
    for (int off = 32; off; off >>= 1) vv += __shfl_down(vv, off);
    if ((t & 63) == 0) a2s[nn] += vv;
  }
  __syncthreads();
  for (int i = t; i < 112; i += 256) atomicAdd(&a2[n0 + i], a2s[i]);
}

// ---------- memory bank: bf16 + norms ----------
__global__ void k_prep_mb(const float* __restrict__ mb, __hip_bfloat16* __restrict__ mbh,
                          float* __restrict__ b2) {
  int m = blockIdx.x, t = threadIdx.x;
  const float* r = mb + (size_t)m * DDIM;
  float s = 0.f;
#pragma unroll
  for (int j = 0; j < 3; ++j) {
    float v = r[t + j * 256];
    s += v * v;
    mbh[(size_t)m * DDIM + t + j * 256] = __float2bfloat16(v);
  }
  for (int o = 32; o; o >>= 1) s += __shfl_down(s, o);
  __shared__ float ws4[4];
  if ((t & 63) == 0) ws4[t >> 6] = s;
  __syncthreads();
  if (t == 0) b2[m] = ws4[0] + ws4[1] + ws4[2] + ws4[3];
}

// ================= 256x256 8-phase bf16 MFMA GEMM, fused min/argmin =================
// A = embh [12544][768], B = mbh [16384][768]; C[n][m] = b2[m] - 2*A[n].B[m]; min over m.
// LDS: 4 buffers x (A 16KB + B 16KB). Tile stored as 16 chunks of 1024B; chunk c holds
// rows [c*16,c*16+16) x 32 k; slot l = (row=l&15, koct=l>>4) -> fragment reads are linear
// in lane (conflict-free); the transpose happens in the global source address of
// global_load_lds (per-lane source, wave-uniform LDS dest + lane*16).
__global__ __launch_bounds__(512) void k_gemm256(const __hip_bfloat16* __restrict__ A,
                                                 const __hip_bfloat16* __restrict__ Bm,
                                                 const float* __restrict__ b2,
                                                 u64* __restrict__ rowmin) {
  __shared__ __align__(16) char ldsc[131072];
  const int t = threadIdx.x;
  const int lane = t & 63;
  const int w = t >> 6;       // 0..7
  const int wr = w >> 2;      // 0..1 : 128-row half
  const int wc = w & 3;       // 0..3 : 64-col quarter

  // bijective XCD swizzle (gridDim.x = 3136 = 8*392)
  int bid = blockIdx.x;
  {
    int cpx = gridDim.x >> 3;
    bid = (bid & 7) * cpx + (bid >> 3);
  }
  const int by = bid % 49;
  const int bx = bid / 49;
  const int n0 = by * 256;
  const int m0 = bx * 256;

  // staging: wave w stages chunks {2w, 2w+1} of A and of B each K-tile
  const int srow = lane & 15;
  const int koct = lane >> 4;
  const __hip_bfloat16* Asrc0 = A + (size_t)(n0 + 2 * w * 16 + srow) * DDIM + koct * 8;
  const __hip_bfloat16* Asrc1 = Asrc0 + (size_t)16 * DDIM;
  const __hip_bfloat16* Bsrc0 = Bm + (size_t)(m0 + 2 * w * 16 + srow) * DDIM + koct * 8;
  const __hip_bfloat16* Bsrc1 = Bsrc0 + (size_t)16 * DDIM;
  const int offA0 = (2 * w) * 1024 + lane * 16;
  const int offA1 = offA0 + 1024;
  const int offB0 = 65536 + offA0;
  const int offB1 = 65536 + offA1;
  const int ro = lane * 16;

  f32x4 acc[8][4] = {};

  // prologue: stage tiles 0 (buf0) and 1 (buf1)
  gload16(Asrc0, ldsc + offA0);
  gload16(Asrc1, ldsc + offA1);
  gload16(Bsrc0, ldsc + offB0);
  gload16(Bsrc1, ldsc + offB1);
  gload16(Asrc0 + 32, ldsc + 16384 + offA0);
  gload16(Asrc1 + 32, ldsc + 16384 + offA1);
  gload16(Bsrc0 + 32, ldsc + 16384 + offB0);
  gload16(Bsrc1 + 32, ldsc + 16384 + offB1);
  asm volatile("s_waitcnt vmcnt(4)" ::: "memory");  // tile 0 resident; tile 1 in flight
  __builtin_amdgcn_s_barrier();

#pragma unroll 4
  for (int kt = 0; kt < NKT; ++kt) {
    const int buf = (kt & 3) << 14;
    const char* Ab = ldsc + buf;
    const char* Bb = ldsc + 65536 + buf;
    bf16x8 a[4], bfr[4];
    // ---------- phase 0: A rows [wr*128, wr*128+64) ----------
#pragma unroll
    for (int i = 0; i < 4; ++i) a[i] = *(const bf16x8*)(Ab + (wr * 8 + i) * 1024 + ro);
#pragma unroll
    for (int j = 0; j < 4; ++j) bfr[j] = *(const bf16x8*)(Bb + (wc * 4 + j) * 1024 + ro);
    if (kt < NKT - 2) {
      const int nbuf = ((kt + 2) & 3) << 14;
      gload16(Asrc0 + (kt + 2) * 32, ldsc + nbuf + offA0);
      gload16(Asrc1 + (kt + 2) * 32, ldsc + nbuf + offA1);
    }
    __builtin_amdgcn_s_barrier();
    asm volatile("s_waitcnt lgkmcnt(0)" ::: "memory");
    __builtin_amdgcn_sched_barrier(0);
    __builtin_amdgcn_s_setprio(1);
#pragma unroll
    for (int i = 0; i < 4; ++i)
#pragma unroll
      for (int j = 0; j < 4; ++j)
        acc[i][j] = __builtin_amdgcn_mfma_f32_16x16x32_bf16(a[i], bfr[j], acc[i][j], 0, 0, 0);
    __builtin_amdgcn_s_setprio(0);
    __builtin_amdgcn_s_barrier();
    // ---------- phase 1: A rows [wr*128+64, wr*128+128) ----------
#pragma unroll
    for (int i = 0; i < 4; ++i) a[i] = *(const bf16x8*)(Ab + (wr * 8 + 4 + i) * 1024 + ro);
    if (kt < NKT - 2) {
      const int nbuf = ((kt + 2) & 3) << 14;
      gload16(Bsrc0 + (kt + 2) * 32, ldsc + nbuf + offB0);
      gload16(Bsrc1 + (kt + 2) * 32, ldsc + nbuf + offB1);
    }
    __builtin_amdgcn_s_barrier();
    asm volatile("s_waitcnt lgkmcnt(0)" ::: "memory");
    __builtin_amdgcn_sched_barrier(0);
    __builtin_amdgcn_s_setprio(1);
#pragma unroll
    for (int i = 0; i < 4; ++i)
#pragma unroll
      for (int j = 0; j < 4; ++j)
        acc[4 + i][j] = __builtin_amdgcn_mfma_f32_16x16x32_bf16(a[i], bfr[j], acc[4 + i][j], 0, 0, 0);
    __builtin_amdgcn_s_setprio(0);
    if (kt < NKT - 1) {
      if (kt < NKT - 2)
        asm volatile("s_waitcnt vmcnt(4)" ::: "memory");  // tile kt+1 resident, kt+2 in flight
      else
        asm volatile("s_waitcnt vmcnt(0)" ::: "memory");  // drain (no more prefetch)
      __builtin_amdgcn_s_barrier();
    }
  }

  // ---------- epilogue: fused min/argmin ----------
  const int lc = lane & 15, lg = lane >> 4;
  float b2v[4];
#pragma unroll
  for (int j = 0; j < 4; ++j) b2v[j] = b2[m0 + wc * 64 + j * 16 + lc];

  u64* rm = (u64*)ldsc;  // [256][4]
  __syncthreads();       // all LDS tile reads done before reuse
#pragma unroll
  for (int i = 0; i < 8; ++i)
#pragma unroll
    for (int r = 0; r < 4; ++r) {
      u64 best = ~0ull;
#pragma unroll
      for (int j = 0; j < 4; ++j) {
        int col = m0 + wc * 64 + j * 16 + lc;
        float v = b2v[j] - 2.f * acc[i][j][r];
        u64 p = packmin(v, col);
        best = best < p ? best : p;
      }
#pragma unroll
      for (int o = 1; o < 16; o <<= 1) {
        u64 o2 = (u64)__shfl_xor((long long)best, o);
        best = best < o2 ? best : o2;
      }
      if (lc == 0) rm[(wr * 128 + i * 16 + lg * 4 + r) * 4 + wc] = best;
    }
  __syncthreads();
  if (t < 256) {
    u64 b0 = rm[t * 4 + 0], b1 = rm[t * 4 + 1], b2x = rm[t * 4 + 2], b3 = rm[t * 4 + 3];
    u64 m01 = b0 < b1 ? b0 : b1;
    u64 m23 = b2x < b3 ? b2x : b3;
    u64 mm = m01 < m23 ? m01 : m23;
    atomicMin(&rowmin[n0 + t], mm);
  }
}

// ---------- small GEMM for candidate rows (stores full distance rows) ----------
__global__ __launch_bounds__(256) void k_gemm_small(const __hip_bfloat16* __restrict__ A,
                                                    const __hip_bfloat16* __restrict__ Bm,
                                                    const float* __restrict__ b2, float* dC) {
  __shared__ short As[128 * 32];
  __shared__ short Bs[128 * 32];
  const int t = threadIdx.x;
  const int m0 = blockIdx.x * 128;
  const int n0 = 0;
  const int w = t >> 6, l = t & 63;
  const int wr = w >> 1, wc = w & 1;
  const int lc = l & 15, lg = l >> 4;
  f32x4 acc[4][4] = {};
  for (int kt = 0; kt < 24; ++kt) {
    const int k0 = kt * 32;
    __syncthreads();
#pragma unroll
    for (int j = 0; j < 2; ++j) {
      int flat = t + j * 256;
      int row = flat >> 2, kc = flat & 3;
      gload16(A + (size_t)(n0 + row) * DDIM + k0 + kc * 8, (char*)As + flat * 16);
      gload16(Bm + (size_t)(m0 + row) * DDIM + k0 + kc * 8, (char*)Bs + flat * 16);
    }
    __syncthreads();
    bf16x8 av[4], bv[4];
#pragma unroll
    for (int i = 0; i < 4; ++i) {
      av[i] = *(const bf16x8*)(As + (wr * 64 + i * 16 + lc) * 32 + lg * 8);
      bv[i] = *(const bf16x8*)(Bs + (wc * 64 + i * 16 + lc) * 32 + lg * 8);
    }
#pragma unroll
    for (int i = 0; i < 4; ++i)
#pragma unroll
      for (int j = 0; j < 4; ++j)
        acc[i][j] = __builtin_amdgcn_mfma_f32_16x16x32_bf16(av[i], bv[j], acc[i][j], 0, 0, 0);
  }
  __syncthreads();
  float b2v[4];
#pragma unroll
  for (int j = 0; j < 4; ++j) b2v[j] = b2[m0 + wc * 64 + j * 16 + lc];
#pragma unroll
  for (int i = 0; i < 4; ++i)
#pragma unroll
    for (int r = 0; r < 4; ++r) {
      int crow = wr * 64 + i * 16 + lg * 4 + r;
#pragma unroll
      for (int j = 0; j < 4; ++j) {
        int col = m0 + wc * 64 + j * 16 + lc;
        dC[(size_t)crow * MTOT + col] = b2v[j] - 2.f * acc[i][j][r];
      }
    }
}

// ---------- patch scores + locations ----------
__global__ void k_scores(const u64* __restrict__ rowmin, const float* __restrict__ a2,
                         float* __restrict__ ps, int* __restrict__ pl) {
  int n = blockIdx.x * 256 + threadIdx.x;
  if (n >= NTOT) return;
  u64 v = rowmin[n];
  float d2 = a2[n] + unpackval(v);
  ps[n] = sqrtf(fmaxf(d2, 0.f));
  pl[n] = (int)(v & 0xffffffffu);
}

// ---------- top-8 candidate patches per batch ----------
__global__ void k_topc(const float* __restrict__ ps, int* __restrict__ cand_n) {
  int b = blockIdx.x, t = threadIdx.x;
  __shared__ float sv[NP];
  __shared__ float rv[256];
  __shared__ int ri[256];
  for (int i = t; i < NP; i += 256) sv[i] = ps[b * NP + i];
  __syncthreads();
  for (int c = 0; c < NCAND; ++c) {
    float bvv = -1e30f; int bi = 0;
    for (int i = t; i < NP; i += 256)
      if (sv[i] > bvv) { bvv = sv[i]; bi = i; }
    rv[t] = bvv; ri[t] = bi;
    __syncthreads();
    for (int s = 128; s; s >>= 1) {
      if (t < s) {
        if (rv[t + s] > rv[t] || (rv[t + s] == rv[t] && ri[t + s] < ri[t])) {
          rv[t] = rv[t + s]; ri[t] = ri[t + s];
        }
      }
      __syncthreads();
    }
    if (t == 0) { cand_n[b * NCAND + c] = b * NP + ri[0]; sv[ri[0]] = -2e30f; }
    __syncthreads();
  }
}

// ---------- gather candidate bf16 rows ----------
__global__ void k_gather(const int* __restrict__ cand_n, const __hip_bfloat16* __restrict__ embh,
                         __hip_bfloat16* __restrict__ ac) {
  int c = blockIdx.x, t = threadIdx.x;
  int n = cand_n[c];
  for (int j = t; j < DDIM; j += 256) ac[(size_t)c * DDIM + j] = embh[(size_t)n * DDIM + j];
}

// ---------- exact refinement of candidate rows ----------
__global__ void k_refine(const float* __restrict__ dcand, const int* __restrict__ cand_n,
                         const float* __restrict__ emb, const float* __restrict__ mbf,
                         const float* __restrict__ a2, const float* __restrict__ b2,
                         float* __restrict__ cscore, int* __restrict__ cloc) {
  int c = blockIdx.x, t = threadIdx.x;
  int n = cand_n[c];
  const float* row = dcand + (size_t)c * MTOT;
  float mn = 1e30f;
  for (int m = t; m < MTOT; m += 256) mn = fminf(mn, row[m]);
  __shared__ float red[256];
  red[t] = mn; __syncthreads();
  for (int s = 128; s; s >>= 1) { if (t < s) red[t] = fminf(red[t], red[t + s]); __syncthreads(); }
  float gmin = red[0];
  __shared__ int list[64];
  __shared__ int cnt;
  if (t == 0) cnt = 0;
  __syncthreads();
  for (int m = t; m < MTOT; m += 256) {
    if (row[m] <= gmin + 8.0f) {
      int p = atomicAdd(&cnt, 1);
      if (p < 64) list[p] = m;
    }
  }
  __syncthreads();
  int L = cnt < 64 ? cnt : 64;
  __shared__ float er[DDIM];
  for (int j = t; j < DDIM; j += 256) er[j] = emb[(size_t)n * DDIM + j];
  __syncthreads();
  int wv = t >> 6, ln = t & 63;
  u64 best = ~0ull;
  for (int li = wv; li < L; li += 4) {
    int m = list[li];
    const float* mr = mbf + (size_t)m * DDIM;
    float s = 0.f;
    for (int j = ln; j < DDIM; j += 64) s += er[j] * mr[j];
    for (int o = 32; o; o >>= 1) s += __shfl_down(s, o);
    if (ln == 0) {
      float d2 = a2[n] + b2[m] - 2.f * s;
      u64 p = packmin(d2, m);
      best = best < p ? best : p;
    }
  }
  __shared__ u64 bw[4];
  if (ln == 0) bw[wv] = best;
  __syncthreads();
  if (t == 0) {
    u64 bb = bw[0];
    for (int i = 1; i < 4; ++i) bb = bb < bw[i] ? bb : bw[i];
    float d2 = unpackval(bb);
    cscore[c] = sqrtf(fmaxf(d2, 0.f));
    cloc[c] = (int)(bb & 0xffffffffu);
  }
}

// ---------- pick per-batch winner ----------
__global__ void k_winner(const int* __restrict__ cand_n, const float* __restrict__ cscore,
                         const int* __restrict__ cloc, float* __restrict__ wscore,
                         int* __restrict__ wloc, int* __restrict__ wn) {
  int b = threadIdx.x;
  if (b < NB) {
    float bs = -1e30f; int bc = 0;
    for (int c = 0; c < NCAND; ++c) {
      float s = cscore[b * NCAND + c];
      if (s > bs) { bs = s; bc = c; }
    }
    wscore[b] = bs;
    wloc[b] = cloc[b * NCAND + bc];
    wn[b] = cand_n[b * NCAND + bc];
  }
}

// ---------- distances nn_sample -> all memory bank rows ----------
__global__ void k_d2nn(const float* __restrict__ mbf, const int* __restrict__ wloc,
                       const float* __restrict__ b2, float* __restrict__ d2nn) {
  __shared__ float nnr[16][64];
  __shared__ float mbr[16][65];
  __shared__ int wl[16];
  int t = threadIdx.x;
  int m0 = blockIdx.x * 16;
  if (t < 16) wl[t] = wloc[t];
  __syncthreads();
  int b = t >> 4, mi = t & 15;
  float acc = 0.f;
  for (int k0 = 0; k0 < DDIM; k0 += 64) {
    __syncthreads();
    for (int i = t; i < 1024; i += 256) {
      int r = i >> 6, kk = i & 63;
      nnr[r][kk] = mbf[(size_t)wl[r] * DDIM + k0 + kk];
      mbr[r][kk] = mbf[(size_t)(m0 + r) * DDIM + k0 + kk];
    }
    __syncthreads();
#pragma unroll 16
    for (int kk = 0; kk < 64; ++kk) acc += nnr[b][kk] * mbr[mi][kk];
  }
  int m = m0 + mi;
  d2nn[b * MTOT + m] = b2[wl[b]] + b2[m] - 2.f * acc;
}

// ---------- top-9 nearest of nn_sample ----------
__global__ void k_top9(const float* __restrict__ d2nn, int* __restrict__ supidx) {
  int b = blockIdx.x, t = threadIdx.x;
  const float* row = d2nn + (size_t)b * MTOT;
  __shared__ u64 red[256];
  __shared__ int chosen[9];
  for (int k = 0; k < 9; ++k) {
    u64 best = ~0ull;
    for (int m = t; m < MTOT; m += 256) {
      bool skip = false;
      for (int j = 0; j < k; ++j)
        if (chosen[j] == m) skip = true;
      if (!skip) {
        u64 p = packmin(row[m], m);
        best = best < p ? best : p;
      }
    }
    red[t] = best; __syncthreads();
    for (int s = 128; s; s >>= 1) {
      if (t < s) red[t] = red[t] < red[t + s] ? red[t] : red[t + s];
      __syncthreads();
    }
    if (t == 0) { chosen[k] = (int)(red[0] & 0xffffffffu); supidx[b * 9 + k] = chosen[k]; }
    __syncthreads();
  }
}

// ---------- anomaly score ----------
__global__ void k_anom(const float* __restrict__ emb, const float* __restrict__ mbf,
                       const int* __restrict__ wn, const int* __restrict__ supidx,
                       const float* __restrict__ wscore, float* __restrict__ out_anom) {
  int b = blockIdx.x, t = threadIdx.x;
  __shared__ float er[DDIM];
  __shared__ float dist[9];
  __shared__ float red[256];
  int n = wn[b];
  for (int j = t; j < DDIM; j += 256) er[j] = emb[(size_t)n * DDIM + j];
  __syncthreads();
  for (int k = 0; k < 9; ++k) {
    int m = supidx[b * 9 + k];
    const float* mr = mbf + (size_t)m * DDIM;
    float s = 0.f;
    for (int j = t; j < DDIM; j += 256) { float d = er[j] - mr[j]; s += d * d; }
    red[t] = s; __syncthreads();
    for (int st = 128; st; st >>= 1) { if (t < st) red[t] += red[t + st]; __syncthreads(); }
    if (t == 0) dist[k] = sqrtf(fmaxf(red[0], 0.f));
    __syncthreads();
  }
  if (t == 0) {
    float mx = dist[0];
    for (int k = 1; k < 9; ++k) mx = fmaxf(mx, dist[k]);
    float sum = 0.f;
    for (int k = 0; k < 9; ++k) sum += expf(dist[k] - mx);
    float w = 1.f - expf(dist[0] - mx) / sum;
    out_anom[b] = w * wscore[b];
  }
}

// ---------- bilinear 28->224 ----------
__global__ void k_bilinear(const float* __restrict__ ps, float* __restrict__ amap) {
  int idx = blockIdx.x * 256 + threadIdx.x;
  if (idx >= NB * OUTHW * OUTHW) return;
  int x = idx % OUTHW, y = (idx / OUTHW) % OUTHW, b = idx / (OUTHW * OUTHW);
  float sy = (y + 0.5f) * 0.125f - 0.5f;
  float sx = (x + 0.5f) * 0.125f - 0.5f;
  int iy = (int)floorf(sy), ix = (int)floorf(sx);
  float fy = sy - iy, fx = sx - ix;
  int y0 = min(27, max(0, iy)), y1 = min(27, max(0, iy + 1));
  int x0 = min(27, max(0, ix)), x1 = min(27, max(0, ix + 1));
  const float* p = ps + b * NP;
  float v = (1.f - fy) * ((1.f - fx) * p[y0 * 28 + x0] + fx * p[y0 * 28 + x1]) +
            fy * ((1.f - fx) * p[y1 * 28 + x0] + fx * p[y1 * 28 + x1]);
  amap[idx] = v;
}

__device__ inline void gauss_coefs(float* g, int t) {
  if (t == 0) {
    float tmp[33]; float s = 0.f;
    for (int j = 0; j < 33; ++j) { float c = (float)(j - 16); tmp[j] = expf(-(c * c) / 32.f); s += tmp[j]; }
    for (int j = 0; j < 33; ++j) g[j] = tmp[j] / s;
  }
}

__global__ void k_blur_h(const float* __restrict__ in, float* __restrict__ out) {
  int by = blockIdx.x;
  int t = threadIdx.x;
  __shared__ float g[33];
  __shared__ float rowbuf[OUTHW];
  gauss_coefs(g, t);
  for (int i = t; i < OUTHW; i += 256) rowbuf[i] = in[(size_t)by * OUTHW + i];
  __syncthreads();
  if (t < OUTHW) {
    float s = 0.f;
#pragma unroll
    for (int j = -16; j <= 16; ++j) {
      int x = t + j;
      x = x < 0 ? -x : (x > 223 ? 446 - x : x);
      s += g[j + 16] * rowbuf[x];
    }
    out[(size_t)by * OUTHW + t] = s;
  }
}

__global__ void k_blur_v(const float* __restrict__ in, float* __restrict__ out) {
  int xt = blockIdx.x, b = blockIdx.y, t = threadIdx.x;
  __shared__ float g[33];
  __shared__ float strip[OUTHW][32];
  gauss_coefs(g, t);
  int x0 = xt * 32;
  for (int i = t; i < OUTHW * 32; i += 256) {
    int y = i >> 5, xx = i & 31;
    strip[y][xx] = in[((size_t)b * OUTHW + y) * OUTHW + x0 + xx];
  }
  __syncthreads();
  for (int i = t; i < OUTHW * 32; i += 256) {
    int y = i >> 5, xx = i & 31;
    float s = 0.f;
#pragma unroll
    for (int j = -16; j <= 16; ++j) {
      int yy = y + j;
      yy = yy < 0 ? -yy : (yy > 223 ? 446 - yy : yy);
      s += g[j + 16] * strip[yy][xx];
    }
    out[((size_t)b * OUTHW + y) * OUTHW + x0 + xx] = s;
  }
}

extern "C" void kernel_launch(void* const* d_in, const int* in_sizes, int n_in,
                              void* d_out, int out_size, void* d_ws, size_t ws_size,
                              hipStream_t stream) {
  const float* feat = (const float*)d_in[0];
  const float* mbf = (const float*)d_in[1];
  float* out = (float*)d_out;

  char* ws = (char*)d_ws;
  size_t off = 0;
  auto alloc = [&](size_t bytes) {
    void* p = ws + off;
    off = (off + bytes + 255) & ~(size_t)255;
    return p;
  };
  float* emb = (float*)alloc((size_t)NTOT * DDIM * 4);
  __hip_bfloat16* embh = (__hip_bfloat16*)alloc((size_t)NTOT * DDIM * 2);
  __hip_bfloat16* mbh = (__hip_bfloat16*)alloc((size_t)MTOT * DDIM * 2);
  float* a2 = (float*)alloc(NTOT * 4);
  float* b2 = (float*)alloc(MTOT * 4);
  u64* rowmin = (u64*)alloc(NTOT * 8);
  float* pscore = (float*)alloc(NTOT * 4);
  int* ploc = (int*)alloc(NTOT * 4);
  __hip_bfloat16* acand = (__hip_bfloat16*)alloc((size_t)TOTCAND * DDIM * 2);
  float* dcand = (float*)alloc((size_t)TOTCAND * MTOT * 4);
  int* cand_n = (int*)alloc(TOTCAND * 4);
  float* cscore = (float*)alloc(TOTCAND * 4);
  int* cloc = (int*)alloc(TOTCAND * 4);
  float* wscore = (float*)alloc(NB * 4);
  int* wloc = (int*)alloc(NB * 4);
  int* wn = (int*)alloc(NB * 4);
  int* supidx = (int*)alloc(NB * 9 * 4);
  float* d2nn = (float*)alloc((size_t)NB * MTOT * 4);
  float* amap_pre = (float*)alloc((size_t)NB * OUTHW * OUTHW * 4);
  float* amap_tmp = (float*)alloc((size_t)NB * OUTHW * OUTHW * 4);

  k_init<<<49, 256, 0, stream>>>(rowmin, a2);
  k_prep_emb<<<dim3(12, 7, 16), 256, 0, stream>>>(feat, emb, embh, a2);
  k_prep_mb<<<MTOT, 256, 0, stream>>>(mbf, mbh, b2);
  k_gemm256<<<3136, 512, 0, stream>>>(embh, mbh, b2, rowmin);
  k_scores<<<49, 256, 0, stream>>>(rowmin, a2, pscore, ploc);
  k_topc<<<NB, 256, 0, stream>>>(pscore, cand_n);
  k_gather<<<TOTCAND, 256, 0, stream>>>(cand_n, embh, acand);
  k_gemm_small<<<dim3(128, 1), 256, 0, stream>>>(acand, mbh, b2, dcand);
  k_refine<<<TOTCAND, 256, 0, stream>>>(dcand, cand_n, emb, mbf, a2, b2, cscore, cloc);
  k_winner<<<1, 256, 0, stream>>>(cand_n, cscore, cloc, wscore, wloc, wn);
  k_d2nn<<<MTOT / 16, 256, 0, stream>>>(mbf, wloc, b2, d2nn);
  k_top9<<<NB, 256, 0, stream>>>(d2nn, supidx);
  k_anom<<<NB, 256, 0, stream>>>(emb, mbf, wn, supidx, wscore, out + NB * OUTHW * OUTHW);
  k_bilinear<<<(NB * OUTHW * OUTHW + 255) / 256, 256, 0, stream>>>(pscore, amap_pre);
  k_blur_h<<<NB * OUTHW, 256, 0, stream>>>(amap_pre, amap_tmp);
  k_blur_v<<<dim3(7, NB), 256, 0, stream>>>(amap_tmp, out);
}